// Round 6
// baseline (697.439 us; speedup 1.0000x reference)
//
#include <hip/hip_runtime.h>
#include <hip/hip_bf16.h>
#include <cstdint>
#include <cstddef>

// ---------------------------------------------------------------------------
// SwinLikeBlock, MI355X gfx950. Inputs f32, output f32.
// N=8, H=W=112, C=256, WS=7 -> 2048 windows x 49 tok, 8 heads x d=32,
// hidden=1024, T=100352.
//
// Round 12: FULL FUSION. Rounds 9-11 showed both kernels latency-bound with
// every pipe <25%; the attn->mlp out round-trip (write 103MB + LN2 read 103MB
// + RMW read 103MB) is pure structural waste. One block per window does
// LN1+qkv+attn+proj+LN2+MLP; the residual (x+attn) lives in LDS f32 and out
// is written exactly once. Buffer rotation (128KB total):
//   yb  32KB: LN1 tile -> attn-out (proj A) -> z = LN2 bf16
//   qkb 64KB: Q|K -> P scratch -> residual f32 (64x256)
//   vtb 32KB: V^T -> h = GELU(fc1) bf16
// MLP work/window grows 1.31x (64 vs 49 rows useful) - cheap at 14% MfmaUtil.
// LDS 16B-group XOR swizzle: group g of row r stored at (g&~7)|((g^r)&7).
// NEVER pad a swizzled buffer (round-10 lesson: padding cancels the XOR).
// ---------------------------------------------------------------------------

typedef __bf16 bf16x8 __attribute__((ext_vector_type(8)));
typedef float f32x4 __attribute__((ext_vector_type(4)));

__device__ __forceinline__ unsigned short f2bf(float f){
    union{float f;uint32_t u;}c;c.f=f;uint32_t u=c.u;u+=0x7fffu+((u>>16)&1u);return (unsigned short)(u>>16);}
__device__ __forceinline__ float gelu_f(float x){ return 0.5f*x*(1.0f+erff(x*0.70710678118654752f)); }
__device__ __forceinline__ int swz(int row,int g){ return (g & ~7) | ((g ^ row) & 7); }

// f32 -> bf16 convert, n4 = count/4
__global__ __launch_bounds__(256) void conv_k(
    const float* __restrict__ src, unsigned short* __restrict__ dst, int n4)
{
    int i = blockIdx.x * 256 + threadIdx.x;
    if (i >= n4) return;
    float4 v = *(const float4*)(src + (size_t)i * 4);
    uint2 o;
    o.x = (uint32_t)f2bf(v.x) | ((uint32_t)f2bf(v.y) << 16);
    o.y = (uint32_t)f2bf(v.z) | ((uint32_t)f2bf(v.w) << 16);
    *(uint2*)(dst + (size_t)i * 4) = o;
}

// ---------------------------------------------------------------------------
// Fused kernel: one block (1024 thr, 16 waves) per window.
// ---------------------------------------------------------------------------
__global__ __launch_bounds__(1024, 4) void fused_k(
    const float* __restrict__ x, const float* __restrict__ g1, const float* __restrict__ b1,
    const unsigned short* __restrict__ Wqkv, const float* __restrict__ bqkv,
    const unsigned short* __restrict__ Wproj, const float* __restrict__ bproj,
    const float* __restrict__ g2, const float* __restrict__ b2,
    const unsigned short* __restrict__ W1, const float* __restrict__ bf1,
    const unsigned short* __restrict__ W2, const float* __restrict__ bf2,
    float* __restrict__ out)
{
    __shared__ __align__(16) unsigned short yb[64 * 256];   // LN1 -> attn-out -> z(LN2)
    __shared__ __align__(16) unsigned short qkb[64 * 512];  // Q|K -> P scratch -> res f32
    __shared__ __align__(16) unsigned short vtb[256 * 64];  // V^T -> h(GELU)
    const int t = threadIdx.x, lane = t & 63, w = t >> 6;   // w = 0..15
    const int quad = lane >> 4, l16 = lane & 15;
    const int widx = blockIdx.x;               // 0..2047
    const int img = widx >> 8, wi = widx & 255;
    const int wy = wi >> 4, wx = wi & 15;
    const size_t ibase = (size_t)img * 12544;
    float* res = (float*)qkb;                  // 64 x 256 f32 residual (phase 4+)

    // ---- phase 1: LN1 into yb (swizzled); loads pipelined ----
    {
        float4 xv[4];
        #pragma unroll
        for (int i = 0; i < 4; ++i) {
            int tok = w + i * 16;
            if (tok < 49) {
                int r = tok / 7, c = tok - r * 7;
                size_t gtok = ibase + (size_t)(wy * 7 + r) * 112 + (wx * 7 + c);
                xv[i] = *(const float4*)(x + gtok * 256 + lane * 4);
            }
        }
        float4 gv = *(const float4*)(g1 + lane * 4);
        float4 bv = *(const float4*)(b1 + lane * 4);
        #pragma unroll
        for (int i = 0; i < 4; ++i) {
            int tok = w + i * 16;
            if (tok < 49) {
                float4 v = xv[i];
                float s = v.x + v.y + v.z + v.w;
                float q = v.x*v.x + v.y*v.y + v.z*v.z + v.w*v.w;
                #pragma unroll
                for (int o = 32; o > 0; o >>= 1) { s += __shfl_xor(s, o); q += __shfl_xor(q, o); }
                float mean = s * (1.f/256.f), var = q * (1.f/256.f) - mean * mean;
                float inv = rsqrtf(var + 1e-5f);
                uint2 pk;
                pk.x = (uint32_t)f2bf((v.x-mean)*inv*gv.x+bv.x) | ((uint32_t)f2bf((v.y-mean)*inv*gv.y+bv.y) << 16);
                pk.y = (uint32_t)f2bf((v.z-mean)*inv*gv.z+bv.z) | ((uint32_t)f2bf((v.w-mean)*inv*gv.w+bv.w) << 16);
                *(uint2*)&yb[tok*256 + swz(tok, lane >> 1)*8 + (lane & 1)*4] = pk;
            }
        }
    }
    {   // zero pad rows 49..63
        uint2 z2; z2.x = 0u; z2.y = 0u;
        for (int i = t; i < 960; i += 1024) {
            int row = 49 + (i >> 6), c4 = (i & 63) * 4;
            *(uint2*)&yb[row*256 + c4] = z2;
        }
    }
    __syncthreads();

    // ---- phase 2: qkv GEMM -> qkb (Q|K swz) / vtb (V^T swz) ----
    {
        const int n0 = w * 48;
        f32x4 acc[4][3] = {};
        #pragma unroll
        for (int ks = 0; ks < 8; ++ks) {
            bf16x8 af[4], bfr[3];
            #pragma unroll
            for (int mt = 0; mt < 4; ++mt) {
                int m = mt * 16 + l16;
                af[mt] = *(const bf16x8*)&yb[m*256 + swz(m, ks*4 + quad)*8];
            }
            #pragma unroll
            for (int nt = 0; nt < 3; ++nt) {
                int n = n0 + nt * 16 + l16;
                bfr[nt] = *(const bf16x8*)(Wqkv + (size_t)n*256 + ks*32 + quad*8);
            }
            #pragma unroll
            for (int mt = 0; mt < 4; ++mt)
                #pragma unroll
                for (int nt = 0; nt < 3; ++nt)
                    acc[mt][nt] = __builtin_amdgcn_mfma_f32_16x16x32_bf16(
                        af[mt], bfr[nt], acc[mt][nt], 0, 0, 0);
        }
        #pragma unroll
        for (int mt = 0; mt < 4; ++mt)
            #pragma unroll
            for (int nt = 0; nt < 3; ++nt) {
                int col = n0 + nt * 16 + l16;
                float bb = bqkv[col];
                #pragma unroll
                for (int r = 0; r < 4; ++r) {
                    int row = mt * 16 + quad * 4 + r;
                    unsigned short val = f2bf(acc[mt][nt][r] + bb);
                    if (col < 512)
                        qkb[row*512 + swz(row, col >> 3)*8 + (col & 7)] = val;
                    else
                        vtb[(col - 512)*64 + swz(col - 512, row >> 3)*8 + (row & 7)] = val;
                }
            }
    }
    __syncthreads();

    // ---- phase 3: attention; waves (h, h+8) -> head h; O -> yb ----
    {
        const float scale = 0.17677669529663687f;   // 32^-0.5
        const int h = w & 7, half = w >> 3;
        unsigned short* pbuf = qkb + w * 1280;      // 32 rows x 40 shorts, per wave

        bf16x8 aq[2], bk[4];
        #pragma unroll
        for (int mtl = 0; mtl < 2; ++mtl) {
            int m = half*32 + mtl*16 + l16;
            aq[mtl] = *(const bf16x8*)&qkb[m*512 + swz(m, h*4 + quad)*8];
        }
        #pragma unroll
        for (int nt = 0; nt < 4; ++nt) {
            int n = nt * 16 + l16;
            bk[nt] = *(const bf16x8*)&qkb[n*512 + swz(n, 32 + h*4 + quad)*8];
        }
        __syncthreads();   // all frag loads done before P overwrites qkb

        f32x4 s[2][4] = {};
        #pragma unroll
        for (int mtl = 0; mtl < 2; ++mtl)
            #pragma unroll
            for (int nt = 0; nt < 4; ++nt)
                s[mtl][nt] = __builtin_amdgcn_mfma_f32_16x16x32_bf16(
                    aq[mtl], bk[nt], s[mtl][nt], 0, 0, 0);

        uint32_t pk01[2][4], pk23[2][4];
        #pragma unroll
        for (int mtl = 0; mtl < 2; ++mtl)
            #pragma unroll
            for (int r = 0; r < 4; ++r) {
                float v0 = s[mtl][0][r];
                float v1 = s[mtl][1][r];
                float v2 = s[mtl][2][r];
                float v3 = (l16 == 0) ? s[mtl][3][r] : -1e30f;  // col 48+l16
                float mxv = fmaxf(fmaxf(v0, v1), fmaxf(v2, v3));
                #pragma unroll
                for (int off = 8; off > 0; off >>= 1) mxv = fmaxf(mxv, __shfl_xor(mxv, off));
                float p0 = __expf((v0 - mxv) * scale);
                float p1 = __expf((v1 - mxv) * scale);
                float p2 = __expf((v2 - mxv) * scale);
                float p3 = __expf((v3 - mxv) * scale);
                float ssum = p0 + p1 + p2 + p3;
                #pragma unroll
                for (int off = 8; off > 0; off >>= 1) ssum += __shfl_xor(ssum, off);
                float inv = 1.f / ssum;
                pk01[mtl][r] = (uint32_t)f2bf(p0*inv) | ((uint32_t)f2bf(p1*inv) << 16);
                pk23[mtl][r] = (uint32_t)f2bf(p2*inv) | ((uint32_t)f2bf(p3*inv) << 16);
            }

        // O = P @ V (32x32/wave, K=64) in two K=32 rounds; P via pbuf (80B pitch)
        f32x4 o[2][2] = {};
        #pragma unroll
        for (int kst = 0; kst < 2; ++kst) {
            #pragma unroll
            for (int mtl = 0; mtl < 2; ++mtl)
                #pragma unroll
                for (int r = 0; r < 4; ++r) {
                    int lr = mtl*16 + quad*4 + r;
                    uint32_t pw = kst ? pk23[mtl][r] : pk01[mtl][r];
                    pbuf[lr*40 + l16]      = (unsigned short)(pw & 0xffffu);
                    pbuf[lr*40 + 16 + l16] = (unsigned short)(pw >> 16);
                }
            bf16x8 ap[2], bv[2];
            #pragma unroll
            for (int mtl = 0; mtl < 2; ++mtl) {
                int m = mtl * 16 + l16;
                ap[mtl] = *(const bf16x8*)&pbuf[m*40 + quad*8];
            }
            #pragma unroll
            for (int nt = 0; nt < 2; ++nt) {
                int c = h*32 + nt*16 + l16;
                bv[nt] = *(const bf16x8*)&vtb[c*64 + swz(c, kst*4 + quad)*8];
            }
            #pragma unroll
            for (int mtl = 0; mtl < 2; ++mtl)
                #pragma unroll
                for (int nt = 0; nt < 2; ++nt)
                    o[mtl][nt] = __builtin_amdgcn_mfma_f32_16x16x32_bf16(
                        ap[mtl], bv[nt], o[mtl][nt], 0, 0, 0);
        }
        // O -> yb (zero pad rows); yb's LN1 content is dead
        #pragma unroll
        for (int mtl = 0; mtl < 2; ++mtl)
            #pragma unroll
            for (int nt = 0; nt < 2; ++nt)
                #pragma unroll
                for (int r = 0; r < 4; ++r) {
                    int row = half*32 + mtl*16 + quad*4 + r;
                    int ch = h*32 + nt*16 + l16;
                    float val = (row < 49) ? o[mtl][nt][r] : 0.f;
                    yb[row*256 + swz(row, ch >> 3)*8 + (ch & 7)] = f2bf(val);
                }
    }
    __syncthreads();   // O complete in yb; P reads done -> qkb free for res

    // ---- phase 4: proj (A=yb) -> res = acc + bproj (f32 in qkb) ----
    {
        const int n0 = w * 16;
        f32x4 acc[4];
        #pragma unroll
        for (int mt = 0; mt < 4; ++mt) acc[mt] = (f32x4){0.f,0.f,0.f,0.f};
        #pragma unroll
        for (int ks = 0; ks < 8; ++ks) {
            bf16x8 af[4], bfr;
            #pragma unroll
            for (int mt = 0; mt < 4; ++mt) {
                int m = mt * 16 + l16;
                af[mt] = *(const bf16x8*)&yb[m*256 + swz(m, ks*4 + quad)*8];
            }
            {
                int n = n0 + l16;
                bfr = *(const bf16x8*)(Wproj + (size_t)n*256 + ks*32 + quad*8);
            }
            #pragma unroll
            for (int mt = 0; mt < 4; ++mt)
                acc[mt] = __builtin_amdgcn_mfma_f32_16x16x32_bf16(
                    af[mt], bfr, acc[mt], 0, 0, 0);
        }
        float bb = bproj[n0 + l16];
        #pragma unroll
        for (int mt = 0; mt < 4; ++mt)
            #pragma unroll
            for (int r = 0; r < 4; ++r) {
                int row = mt * 16 + quad * 4 + r;
                res[row*256 + n0 + l16] = acc[mt][r] + bb;
            }
    }
    __syncthreads();

    // ---- phase 5: res += x; LN2(res) -> z in yb ----
    {
        const int row = t >> 4, i = t & 15;     // 16 threads per row
        float4 v0, v1, v2, v3;
        v0 = *(const float4*)&res[row*256 + i*4];
        v1 = *(const float4*)&res[row*256 + i*4 + 64];
        v2 = *(const float4*)&res[row*256 + i*4 + 128];
        v3 = *(const float4*)&res[row*256 + i*4 + 192];
        if (row < 49) {
            int rr = row / 7, cc = row - rr * 7;
            size_t gtok = ibase + (size_t)(wy * 7 + rr) * 112 + (wx * 7 + cc);
            const float* xr = x + gtok * 256;
            float4 a0 = *(const float4*)(xr + i*4);
            float4 a1 = *(const float4*)(xr + i*4 + 64);
            float4 a2 = *(const float4*)(xr + i*4 + 128);
            float4 a3 = *(const float4*)(xr + i*4 + 192);
            v0.x+=a0.x; v0.y+=a0.y; v0.z+=a0.z; v0.w+=a0.w;
            v1.x+=a1.x; v1.y+=a1.y; v1.z+=a1.z; v1.w+=a1.w;
            v2.x+=a2.x; v2.y+=a2.y; v2.z+=a2.z; v2.w+=a2.w;
            v3.x+=a3.x; v3.y+=a3.y; v3.z+=a3.z; v3.w+=a3.w;
            *(float4*)&res[row*256 + i*4]       = v0;
            *(float4*)&res[row*256 + i*4 + 64]  = v1;
            *(float4*)&res[row*256 + i*4 + 128] = v2;
            *(float4*)&res[row*256 + i*4 + 192] = v3;
        }
        float s = v0.x+v0.y+v0.z+v0.w + v1.x+v1.y+v1.z+v1.w
                + v2.x+v2.y+v2.z+v2.w + v3.x+v3.y+v3.z+v3.w;
        float q = v0.x*v0.x+v0.y*v0.y+v0.z*v0.z+v0.w*v0.w
                + v1.x*v1.x+v1.y*v1.y+v1.z*v1.z+v1.w*v1.w
                + v2.x*v2.x+v2.y*v2.y+v2.z*v2.z+v2.w*v2.w
                + v3.x*v3.x+v3.y*v3.y+v3.z*v3.z+v3.w*v3.w;
        #pragma unroll
        for (int off = 8; off > 0; off >>= 1) { s += __shfl_xor(s, off); q += __shfl_xor(q, off); }
        float mean = s * (1.f/256.f), var = q * (1.f/256.f) - mean * mean;
        float inv = rsqrtf(var + 1e-5f);
        #pragma unroll
        for (int j = 0; j < 4; ++j) {
            int c = i*4 + j*64;
            float4 vv = (j==0)?v0:(j==1)?v1:(j==2)?v2:v3;
            float4 gv = *(const float4*)(g2 + c);
            float4 bv = *(const float4*)(b2 + c);
            uint2 pk;
            pk.x = (uint32_t)f2bf((vv.x-mean)*inv*gv.x+bv.x) | ((uint32_t)f2bf((vv.y-mean)*inv*gv.y+bv.y) << 16);
            pk.y = (uint32_t)f2bf((vv.z-mean)*inv*gv.z+bv.z) | ((uint32_t)f2bf((vv.w-mean)*inv*gv.w+bv.w) << 16);
            *(uint2*)&yb[row*256 + swz(row, c >> 3)*8 + (c & 7)] = pk;
        }
    }
    __syncthreads();

    // ---- phase 6: MLP, 4 hidden chunks of 256; z in yb, h in vtb ----
    unsigned short* hb = vtb;
    f32x4 acc2[4] = {};
    const int ncol = w * 16 + l16;             // this lane's output col (fc2) / fc1 col base
    for (int c = 0; c < 4; ++c) {
        const int hc0 = c * 256;
        f32x4 acc1[4] = {};
        bf16x8 bnx = *(const bf16x8*)(W1 + (size_t)(hc0 + ncol)*256 + quad*8);
        #pragma unroll
        for (int ks = 0; ks < 8; ++ks) {
            bf16x8 af[4], bcur = bnx;
            if (ks < 7)
                bnx = *(const bf16x8*)(W1 + (size_t)(hc0 + ncol)*256 + (ks+1)*32 + quad*8);
            #pragma unroll
            for (int mt = 0; mt < 4; ++mt) {
                int m = mt * 16 + l16;
                af[mt] = *(const bf16x8*)&yb[m*256 + swz(m, ks*4 + quad)*8];
            }
            #pragma unroll
            for (int mt = 0; mt < 4; ++mt)
                acc1[mt] = __builtin_amdgcn_mfma_f32_16x16x32_bf16(
                    af[mt], bcur, acc1[mt], 0, 0, 0);
        }
        __syncthreads();                      // prev chunk's hb reads done
        {
            float bb = bf1[hc0 + ncol];
            #pragma unroll
            for (int mt = 0; mt < 4; ++mt)
                #pragma unroll
                for (int r = 0; r < 4; ++r) {
                    int row = mt * 16 + quad * 4 + r;
                    hb[row*256 + swz(row, ncol >> 3)*8 + (ncol & 7)] =
                        f2bf(gelu_f(acc1[mt][r] + bb));
                }
        }
        __syncthreads();
        bf16x8 b2x = *(const bf16x8*)(W2 + (size_t)ncol*1024 + hc0 + quad*8);
        #pragma unroll
        for (int ks = 0; ks < 8; ++ks) {
            bf16x8 af[4], bcur = b2x;
            if (ks < 7)
                b2x = *(const bf16x8*)(W2 + (size_t)ncol*1024 + hc0 + (ks+1)*32 + quad*8);
            #pragma unroll
            for (int mt = 0; mt < 4; ++mt) {
                int m = mt * 16 + l16;
                af[mt] = *(const bf16x8*)&hb[m*256 + swz(m, ks*4 + quad)*8];
            }
            #pragma unroll
            for (int mt = 0; mt < 4; ++mt)
                acc2[mt] = __builtin_amdgcn_mfma_f32_16x16x32_bf16(
                    af[mt], bcur, acc2[mt], 0, 0, 0);
        }
    }
    // ---- epilogue: out = res + acc2 + bf2 (single write, 64B sectors) ----
    {
        float bb = bf2[ncol];
        #pragma unroll
        for (int mt = 0; mt < 4; ++mt)
            #pragma unroll
            for (int r = 0; r < 4; ++r) {
                int row = mt * 16 + quad * 4 + r;
                if (row < 49) {
                    int rr = row / 7, cc = row - rr * 7;
                    size_t gtok = ibase + (size_t)(wy * 7 + rr) * 112 + (wx * 7 + cc);
                    out[gtok * 256 + ncol] = acc2[mt][r] + bb + res[row*256 + ncol];
                }
            }
    }
}

// ---------------------------------------------------------------------------
extern "C" void kernel_launch(void* const* d_in, const int* in_sizes, int n_in,
                              void* d_out, int out_size, void* d_ws, size_t ws_size,
                              hipStream_t stream)
{
    const float* x      = (const float*)d_in[0];
    // d_in[1]=H, d_in[2]=W : compile-time constants (112).
    const float* g1     = (const float*)d_in[3];
    const float* b1     = (const float*)d_in[4];
    const float* w_qkv  = (const float*)d_in[5];
    const float* b_qkv  = (const float*)d_in[6];
    const float* w_proj = (const float*)d_in[7];
    const float* b_proj = (const float*)d_in[8];
    const float* g2     = (const float*)d_in[9];
    const float* b2     = (const float*)d_in[10];
    const float* w_fc1  = (const float*)d_in[11];
    const float* b_fc1  = (const float*)d_in[12];
    const float* w_fc2  = (const float*)d_in[13];
    const float* b_fc2  = (const float*)d_in[14];
    float* out = (float*)d_out;                      // f32 output

    // ws: converted bf16 weights only — 786432 elems = 1.5 MiB
    unsigned short* cWqkv  = (unsigned short*)d_ws;  // 196608
    unsigned short* cWproj = cWqkv  + 196608;        // 65536
    unsigned short* cWfc1  = cWproj + 65536;         // 262144
    unsigned short* cWfc2  = cWfc1  + 262144;        // 262144

    conv_k<<<192, 256, 0, stream>>>(w_qkv,  cWqkv,  49152);
    conv_k<<<64,  256, 0, stream>>>(w_proj, cWproj, 16384);
    conv_k<<<256, 256, 0, stream>>>(w_fc1,  cWfc1,  65536);
    conv_k<<<256, 256, 0, stream>>>(w_fc2,  cWfc2,  65536);

    fused_k<<<2048, 1024, 0, stream>>>(x, g1, b1, cWqkv, b_qkv, cWproj, b_proj,
                                       g2, b2, cWfc1, b_fc1, cWfc2, b_fc2, out);
}